// Round 4
// baseline (218.393 us; speedup 1.0000x reference)
//
#include <hip/hip_runtime.h>
#include <hip/hip_bf16.h>
#include <math.h>

#define T_ 2048
#define C_ 1024
#define H_ 128
#define NB 8
#define WN 131072                 // 128*1024 per weight
#define SC 0.08838834764831845f   // 1/sqrt(128)

typedef __attribute__((ext_vector_type(8))) short bf16x8;
typedef __attribute__((ext_vector_type(8))) unsigned short u16x8;
typedef __attribute__((ext_vector_type(4))) float f32x4;

#define MFMA16(a,b,c) __builtin_amdgcn_mfma_f32_16x16x32_bf16((a),(b),(c),0,0,0)

__device__ __forceinline__ unsigned short f2bf(float f) {
    union { float f; unsigned u; } v; v.f = f;
    unsigned r = v.u + 0x7fffu + ((v.u >> 16) & 1u);
    return (unsigned short)(r >> 16);
}
__device__ __forceinline__ float bf2f(unsigned short u) {
    union { unsigned u; float f; } v; v.u = ((unsigned)u) << 16; return v.f;
}
__device__ __forceinline__ unsigned pk2bf(float a, float b) {
    __hip_bfloat162 h = __float22bfloat162_rn(float2{a, b});
    union { __hip_bfloat162 h; unsigned u; } v; v.h = h; return v.u;
}
// async global->LDS, 16B per lane; lds dest = uniform base + laneid*16
__device__ __forceinline__ void gld16(void* lds, const void* g) {
    __builtin_amdgcn_global_load_lds(
        (const __attribute__((address_space(1))) unsigned*)g,
        (__attribute__((address_space(3))) unsigned*)lds, 16, 0, 0);
}

// ---------- kernel 1: W fp32 -> bf16 (Wq pre-scaled by 1/sqrt(H)) ----------
__global__ __launch_bounds__(256) void wconv(const float* __restrict__ Wq,
                                             const float* __restrict__ Wk,
                                             const float* __restrict__ Wv,
                                             unsigned short* __restrict__ Wb) {
    int e = (blockIdx.x * 256 + threadIdx.x) * 8;       // < 393216
    int which = e >> 17;
    int off = e & (WN - 1);
    const float* src = (which == 0) ? Wq : (which == 1 ? Wk : Wv);
    float s = (which == 0) ? SC : 1.0f;
    const float4* p = (const float4*)(src + off);
    float4 a = p[0], b = p[1];
    uint4 o = { pk2bf(a.x * s, a.y * s), pk2bf(a.z * s, a.w * s),
                pk2bf(b.x * s, b.y * s), pk2bf(b.z * s, b.w * s) };
    *(uint4*)(Wb + e) = o;
}

// ---------- kernel 2: fused QKV projection, LDS-free register streaming ----------
// grid 512: m-tile 32, n = 384 (q|k|v) per block (x read once), no barriers.
// A/B fragments loaded straight from row-major global (lane l16 = row, quad*8 = k).
__global__ __launch_bounds__(256) void proj(const float* __restrict__ x,
                                            const unsigned short* __restrict__ Wb,
                                            unsigned short* __restrict__ Q,
                                            unsigned short* __restrict__ K,
                                            unsigned short* __restrict__ V) {
    const int tid  = threadIdx.x;
    const int wave = tid >> 6, lane = tid & 63;
    const int quad = lane >> 4, l16 = lane & 15;
    const int m0   = blockIdx.x * 32;

    f32x4 acc[2][6];
    #pragma unroll
    for (int i = 0; i < 2; i++)
        #pragma unroll
        for (int j = 0; j < 6; j++) acc[i][j] = {0.f, 0.f, 0.f, 0.f};

    const float* xp0 = x + (size_t)(m0 + l16) * C_ + quad * 8;        // A rows 0..15
    const float* xp1 = x + (size_t)(m0 + 16 + l16) * C_ + quad * 8;   // A rows 16..31
    const unsigned short* wp = Wb + (size_t)(wave * 96 + l16) * C_ + quad * 8;

    #pragma unroll 2
    for (int ko = 0; ko < C_; ko += 32) {
        // A-frags: 8 consecutive fp32 from each of rows l16, l16+16 -> bf16x8
        float4 a00 = *(const float4*)(xp0 + ko);
        float4 a01 = *(const float4*)(xp0 + ko + 4);
        float4 a10 = *(const float4*)(xp1 + ko);
        float4 a11 = *(const float4*)(xp1 + ko + 4);
        union { uint4 u; bf16x8 h; } af0, af1;
        af0.u = uint4{ pk2bf(a00.x, a00.y), pk2bf(a00.z, a00.w),
                       pk2bf(a01.x, a01.y), pk2bf(a01.z, a01.w) };
        af1.u = uint4{ pk2bf(a10.x, a10.y), pk2bf(a10.z, a10.w),
                       pk2bf(a11.x, a11.y), pk2bf(a11.z, a11.w) };
        // B-frags straight from Wb (L1/L2-resident), 16 B per lane
        #pragma unroll
        for (int nf = 0; nf < 6; nf++) {
            bf16x8 bw = *(const bf16x8*)(wp + (size_t)nf * 16 * C_ + ko);
            acc[0][nf] = MFMA16(af0.h, bw, acc[0][nf]);
            acc[1][nf] = MFMA16(af1.h, bw, acc[1][nf]);
        }
    }

    #pragma unroll
    for (int nf = 0; nf < 6; nf++) {
        int nb = wave * 96 + nf * 16;
        int which = nb >> 7;                   // frag-uniform
        unsigned short* dst = (which == 0) ? Q : (which == 1 ? K : V);
        int c = (nb & 127) + l16;
        #pragma unroll
        for (int mf = 0; mf < 2; mf++)
            #pragma unroll
            for (int r = 0; r < 4; r++)
                dst[(size_t)(m0 + mf * 16 + quad * 4 + r) * H_ + c] = f2bf(acc[mf][nf][r]);
    }
}

// ---------- kernel 3: split-K flash causal attention (S^T layout) ----------
// grid (256, 8): bx -> {s = bx&7, qt = 31-(bx>>3)}, y = batch. K-tile 64, split 256.
__global__ __launch_bounds__(256, 3) void attn(const unsigned short* __restrict__ Qg,
                                               const unsigned short* __restrict__ Kg,
                                               const unsigned short* __restrict__ Vg,
                                               unsigned short* __restrict__ Ob,
                                               float* __restrict__ Ml) {
    const int bx = blockIdx.x;
    const int s  = bx & 7, qt = 31 - (bx >> 3);
    const int b  = blockIdx.y;
    const int qbase = qt * 64, kstart = s * 256;
    if (kstart > qbase) return;                               // inactive split
    const int kend  = (kstart + 256 < qbase + 64) ? kstart + 256 : qbase + 64;
    const int niter = (kend - kstart) >> 6;

    __shared__ unsigned short Ks[4][64][32];   // 16 KB (chunked by H/32)
    __shared__ unsigned short Vt[128 * 64];    // 16 KB (packed-pair XOR-swizzled transpose)
    __shared__ unsigned short Ps[4][16][64];   //  8 KB (per-wave P^T->A, XOR-swizzled)

    const int tid = threadIdx.x, wave = tid >> 6, lane = tid & 63;
    const int quad = lane >> 4, l16 = lane & 15;
    const size_t base = (size_t)b * T_ * H_;

    // K staging (async) + V regs
    const unsigned short* ksrc = Kg + base + (size_t)(kstart + (lane >> 2)) * H_ + wave * 32 + (lane & 3) * 8;
    #pragma unroll
    for (int p = 0; p < 4; p++) gld16(&Ks[wave][p * 16][0], ksrc + (size_t)p * 16 * H_);
    const unsigned short* vsrc = Vg + base + (size_t)(kstart + wave * 8 + quad * 2) * H_ + l16 * 8;
    u16x8 vr[2][2];
    vr[0][0] = *(const u16x8*)vsrc;             vr[0][1] = *(const u16x8*)(vsrc + H_);
    vr[1][0] = *(const u16x8*)(vsrc + 32 * H_); vr[1][1] = *(const u16x8*)(vsrc + 33 * H_);

    // Q fragments straight from global (loop-invariant)
    bf16x8 qf[4];
    const unsigned short* qp = Qg + base + (size_t)(qbase + wave * 16 + l16) * H_ + quad * 8;
    #pragma unroll
    for (int kk = 0; kk < 4; kk++) qf[kk] = *(const bf16x8*)(qp + kk * 32);

    f32x4 o[8];
    #pragma unroll
    for (int i = 0; i < 8; i++) o[i] = {0.f, 0.f, 0.f, 0.f};
    float m_i = -INFINITY, l_i = 0.f;
    const int swz = (l16 & 7) << 3;
    const int qg = qbase + wave * 16 + l16;    // this lane's q-row

    __syncthreads();                           // Ks(0) landed (barrier drains vmcnt)

    // write Vt(0): packed pairs, XOR swizzle (2-way = free)
    #pragma unroll
    for (int g = 0; g < 2; g++) {
        int t0 = wave * 8 + g * 32 + quad * 2;
        int t8 = t0 >> 3;
        #pragma unroll
        for (int j = 0; j < 8; j++) {
            int h = l16 * 8 + j;
            unsigned pk = (unsigned)(unsigned short)vr[g][0][j] | ((unsigned)(unsigned short)vr[g][1][j] << 16);
            int blk = (t8 ^ (h & 7) ^ ((h >> 3) & 7)) & 7;
            *(unsigned*)&Vt[h * 64 + blk * 8 + (t0 & 7)] = pk;
        }
    }

    for (int kt = 0; ; kt++) {
        const int kbase = kstart + kt * 64;
        // ---- S^T = K Q^T : rows k (quad*4+r within nf*16), col q = l16
        f32x4 st[4];
        #pragma unroll
        for (int nf = 0; nf < 4; nf++) st[nf] = {0.f, 0.f, 0.f, 0.f};
        #pragma unroll
        for (int kk = 0; kk < 4; kk++)
            #pragma unroll
            for (int nf = 0; nf < 4; nf++) {
                bf16x8 kfr = *(bf16x8*)&Ks[kk][nf * 16 + l16][quad * 8];
                st[nf] = MFMA16(kfr, qf[kk], st[nf]);
            }
        // ---- causal mask (diagonal region only; block-uniform branch)
        if (kbase + 64 > qbase) {
            #pragma unroll
            for (int nf = 0; nf < 4; nf++) {
                int kg = kbase + nf * 16 + quad * 4;
                #pragma unroll
                for (int r = 0; r < 4; r++)
                    if (kg + r > qg) st[nf][r] = -INFINITY;
            }
        }
        // ---- online softmax: per-lane q, 15 reg-max + 2 shuffles
        float mx = st[0][0];
        #pragma unroll
        for (int nf = 0; nf < 4; nf++)
            #pragma unroll
            for (int r = 0; r < 4; r++) mx = fmaxf(mx, st[nf][r]);
        mx = fmaxf(mx, __shfl_xor(mx, 16, 64));
        mx = fmaxf(mx, __shfl_xor(mx, 32, 64));
        float mnew = fmaxf(m_i, mx);
        float al = __expf(m_i - mnew);
        m_i = mnew;
        float rs = 0.f;
        #pragma unroll
        for (int nf = 0; nf < 4; nf++)
            #pragma unroll
            for (int r = 0; r < 4; r++) {
                float e = __expf(st[nf][r] - mnew);
                st[nf][r] = e; rs += e;
            }
        rs += __shfl_xor(rs, 16, 64);
        rs += __shfl_xor(rs, 32, 64);
        l_i = al * l_i + rs;
        // ---- P^T -> Ps (A-layout source), packed b64 writes, swizzled
        #pragma unroll
        for (int nf = 0; nf < 4; nf++) {
            uint2 pk = { pk2bf(st[nf][0], st[nf][1]), pk2bf(st[nf][2], st[nf][3]) };
            *(uint2*)&Ps[wave][l16][(nf * 16 + quad * 4) ^ swz] = pk;
        }
        // ---- rescale O (alpha lives at lane l16=q; O rows are quad*4+r)
        float a0 = __shfl(al, quad * 4 + 0, 64), a1 = __shfl(al, quad * 4 + 1, 64);
        float a2 = __shfl(al, quad * 4 + 2, 64), a3 = __shfl(al, quad * 4 + 3, 64);
        #pragma unroll
        for (int i = 0; i < 8; i++) {
            o[i][0] *= a0; o[i][1] *= a1; o[i][2] *= a2; o[i][3] *= a3;
        }
        __syncthreads();   // B: Vt complete, all Ks reads done

        const bool more = (kt + 1 < niter);
        if (more) {        // async prefetch next K; V tile -> regs
            ksrc += 64 * H_;
            #pragma unroll
            for (int p = 0; p < 4; p++) gld16(&Ks[wave][p * 16][0], ksrc + (size_t)p * 16 * H_);
            vsrc += 64 * H_;
            vr[0][0] = *(const u16x8*)vsrc;             vr[0][1] = *(const u16x8*)(vsrc + H_);
            vr[1][0] = *(const u16x8*)(vsrc + 32 * H_); vr[1][1] = *(const u16x8*)(vsrc + 33 * H_);
        }
        // ---- O += P V (overlaps in-flight prefetch)
        bf16x8 pa0 = *(bf16x8*)&Ps[wave][l16][(quad * 8) ^ swz];
        bf16x8 pa1 = *(bf16x8*)&Ps[wave][l16][(32 + quad * 8) ^ swz];
        #pragma unroll
        for (int nf = 0; nf < 8; nf++) {
            int h = nf * 16 + l16;
            int ex = (h & 7) ^ ((h >> 3) & 7);
            bf16x8 v0 = *(bf16x8*)&Vt[h * 64 + ((quad ^ ex) & 7) * 8];
            bf16x8 v1 = *(bf16x8*)&Vt[h * 64 + (((quad + 4) ^ ex) & 7) * 8];
            o[nf] = MFMA16(pa0, v0, o[nf]);
            o[nf] = MFMA16(pa1, v1, o[nf]);
        }
        if (!more) break;
        __syncthreads();   // A: next Ks landed; Vt free to overwrite
        #pragma unroll
        for (int g = 0; g < 2; g++) {
            int t0 = wave * 8 + g * 32 + quad * 2;
            int t8 = t0 >> 3;
            #pragma unroll
            for (int j = 0; j < 8; j++) {
                int h = l16 * 8 + j;
                unsigned pk = (unsigned)(unsigned short)vr[g][0][j] | ((unsigned)(unsigned short)vr[g][1][j] << 16);
                int blk = (t8 ^ (h & 7) ^ ((h >> 3) & 7)) & 7;
                *(unsigned*)&Vt[h * 64 + blk * 8 + (t0 & 7)] = pk;
            }
        }
    }

    // ---- partial epilogue: normalized O (bf16) + (m,l) per row
    const int g2 = qt >> 2;
    const int Pq = 2 * g2 * (g2 + 1) + (qt & 3) * (g2 + 1);   // prefix of split counts
    const int slot = (Pq + s) * NB + b;
    float lq[4];
    #pragma unroll
    for (int r = 0; r < 4; r++) lq[r] = __shfl(l_i, quad * 4 + r, 64);
    const size_t obase = (size_t)slot * 64 * 128;
    #pragma unroll
    for (int r = 0; r < 4; r++) {
        float invl = 1.0f / lq[r];
        #pragma unroll
        for (int nf = 0; nf < 8; nf++)
            Ob[obase + (size_t)(wave * 16 + quad * 4 + r) * 128 + nf * 16 + l16] = f2bf(o[nf][r] * invl);
    }
    if (lane < 16) {
        int ridx = slot * 64 + wave * 16 + l16;
        Ml[ridx * 2]     = m_i;
        Ml[ridx * 2 + 1] = l_i;
    }
}

// ---------- kernel 4: merge splits (log-sum-exp recombination) ----------
__global__ __launch_bounds__(256) void merge(const unsigned short* __restrict__ Ob,
                                             const float* __restrict__ Ml,
                                             float* __restrict__ out) {
    const int qt = blockIdx.x, b = blockIdx.y;
    const int g = qt >> 2;
    const int Pq = 2 * g * (g + 1) + (qt & 3) * (g + 1);
    const int ns = g + 1;
    const int tid = threadIdx.x;
    const int row = tid >> 2, c0 = (tid & 3) * 32;

    float mv[8], lv[8], mg = -INFINITY;
    for (int s2 = 0; s2 < ns; s2++) {
        int slot = (Pq + s2) * NB + b;
        mv[s2] = Ml[(slot * 64 + row) * 2];
        lv[s2] = Ml[(slot * 64 + row) * 2 + 1];
        mg = fmaxf(mg, mv[s2]);
    }
    float L = 0.f, w[8];
    for (int s2 = 0; s2 < ns; s2++) { w[s2] = lv[s2] * __expf(mv[s2] - mg); L += w[s2]; }
    float inv = 1.0f / L;

    float accv[32];
    #pragma unroll
    for (int i = 0; i < 32; i++) accv[i] = 0.f;
    for (int s2 = 0; s2 < ns; s2++) {
        int slot = (Pq + s2) * NB + b;
        const unsigned short* op = Ob + ((size_t)(slot * 64 + row)) * 128 + c0;
        #pragma unroll
        for (int cc = 0; cc < 4; cc++) {
            u16x8 v = *(const u16x8*)(op + cc * 8);
            #pragma unroll
            for (int j = 0; j < 8; j++) accv[cc * 8 + j] += w[s2] * bf2f(v[j]);
        }
    }
    float* od = out + ((size_t)(b * T_ + qt * 64 + row)) * 128 + c0;
    #pragma unroll
    for (int cc = 0; cc < 8; cc++) {
        float4 w4 = { accv[cc*4] * inv, accv[cc*4+1] * inv, accv[cc*4+2] * inv, accv[cc*4+3] * inv };
        *(float4*)(od + cc * 4) = w4;
    }
}

extern "C" void kernel_launch(void* const* d_in, const int* in_sizes, int n_in,
                              void* d_out, int out_size, void* d_ws, size_t ws_size,
                              hipStream_t stream) {
    const float* x  = (const float*)d_in[0];
    const float* Wq = (const float*)d_in[1];
    const float* Wk = (const float*)d_in[2];
    const float* Wv = (const float*)d_in[3];

    char* ws = (char*)d_ws;
    unsigned short* Wb = (unsigned short*)ws;                          // 0.75 MB @ 0
    unsigned short* Q  = (unsigned short*)(ws + (size_t) 1 * (1u << 20)); // 4 MB
    unsigned short* K  = (unsigned short*)(ws + (size_t) 5 * (1u << 20));
    unsigned short* V  = (unsigned short*)(ws + (size_t) 9 * (1u << 20));
    unsigned short* Ob = (unsigned short*)(ws + (size_t)13 * (1u << 20)); // 18.9 MB (1152 slots)
    float*          Ml = (float*)(ws + (size_t)32 * (1u << 20));          // 0.6 MB
    float* out = (float*)d_out;

    hipLaunchKernelGGL(wconv, dim3(192), dim3(256), 0, stream, Wq, Wk, Wv, Wb);
    hipLaunchKernelGGL(proj,  dim3(512), dim3(256), 0, stream, x, Wb, Q, K, V);
    hipLaunchKernelGGL(attn,  dim3(256, NB), dim3(256), 0, stream, Q, K, V, Ob, Ml);
    hipLaunchKernelGGL(merge, dim3(32, NB), dim3(256), 0, stream, Ob, Ml, out);
}

// Round 5
// 180.186 us; speedup vs baseline: 1.2120x; 1.2120x over previous
//
#include <hip/hip_runtime.h>
#include <hip/hip_bf16.h>
#include <math.h>

#define T_ 2048
#define C_ 1024
#define H_ 128
#define NB 8
#define WN 131072                 // 128*1024 per weight
#define SC 0.08838834764831845f   // 1/sqrt(128)

typedef __attribute__((ext_vector_type(8))) short bf16x8;
typedef __attribute__((ext_vector_type(8))) unsigned short u16x8;
typedef __attribute__((ext_vector_type(4))) float f32x4;

#define MFMA16(a,b,c) __builtin_amdgcn_mfma_f32_16x16x32_bf16((a),(b),(c),0,0,0)

__device__ __forceinline__ unsigned short f2bf(float f) {
    union { float f; unsigned u; } v; v.f = f;
    unsigned r = v.u + 0x7fffu + ((v.u >> 16) & 1u);
    return (unsigned short)(r >> 16);
}
__device__ __forceinline__ float bf2f(unsigned short u) {
    union { unsigned u; float f; } v; v.u = ((unsigned)u) << 16; return v.f;
}
__device__ __forceinline__ unsigned pk2bf(float a, float b) {
    __hip_bfloat162 h = __float22bfloat162_rn(float2{a, b});
    union { __hip_bfloat162 h; unsigned u; } v; v.h = h; return v.u;
}
// async global->LDS, 16B per lane; lds dest = uniform base + laneid*16
__device__ __forceinline__ void gld16(void* lds, const void* g) {
    __builtin_amdgcn_global_load_lds(
        (const __attribute__((address_space(1))) unsigned*)g,
        (__attribute__((address_space(3))) unsigned*)lds, 16, 0, 0);
}

// ---------- kernel 1: W fp32 -> bf16 (Wq pre-scaled by 1/sqrt(H)) ----------
__global__ __launch_bounds__(256) void wconv(const float* __restrict__ Wq,
                                             const float* __restrict__ Wk,
                                             const float* __restrict__ Wv,
                                             unsigned short* __restrict__ Wb) {
    int e = (blockIdx.x * 256 + threadIdx.x) * 8;       // < 393216
    int which = e >> 17;
    int off = e & (WN - 1);
    const float* src = (which == 0) ? Wq : (which == 1 ? Wk : Wv);
    float s = (which == 0) ? SC : 1.0f;
    const float4* p = (const float4*)(src + off);
    float4 a = p[0], b = p[1];
    uint4 o = { pk2bf(a.x * s, a.y * s), pk2bf(a.z * s, a.w * s),
                pk2bf(b.x * s, b.y * s), pk2bf(b.z * s, b.w * s) };
    *(uint4*)(Wb + e) = o;
}

// ---------- kernel 2: QKV projection, m64 x n128 tiles, BK=64, dbuf ----------
// grid (3, 256): bx = Q/K/V select, by = m-tile. 48 KB LDS -> 3 blocks/CU.
// W staged async via gld16; x (fp32) loaded to regs pre-compute, converted and
// written to the other buffer post-compute (latency hidden by 16 MFMAs x 12 waves/CU).
__global__ __launch_bounds__(256, 3) void proj(const float* __restrict__ x,
                                               const unsigned short* __restrict__ Wb,
                                               unsigned short* __restrict__ Q,
                                               unsigned short* __restrict__ K,
                                               unsigned short* __restrict__ V) {
    __shared__ unsigned short Xs[2][2][64][32];    // 16 KB
    __shared__ unsigned short Ws[2][2][128][32];   // 32 KB

    const int tid  = threadIdx.x;
    const int wave = tid >> 6, lane = tid & 63;
    const int quad = lane >> 4, l16 = lane & 15;
    const int nsel = blockIdx.x;
    const int m0   = blockIdx.y * 64;
    const int n0   = nsel * 128;

    f32x4 acc[4][2];
    #pragma unroll
    for (int i = 0; i < 4; i++)
        #pragma unroll
        for (int j = 0; j < 2; j++) acc[i][j] = {0.f, 0.f, 0.f, 0.f};

    // W staging: wave covers rows n0+wave*32 .. +31; lane -> row (lane>>2), col (lane&3)*8
    const unsigned short* wsrc = Wb + (size_t)(n0 + wave * 32 + (lane >> 2)) * C_ + (lane & 3) * 8;
    // x staging: thread t -> row t>>2, col-group t&3 (16 fp32 each)
    const int xrow = tid >> 2, xg = tid & 3;
    const int xkk = xg >> 1, xoff = (xg & 1) * 16;
    const float* xsrc = x + (size_t)(m0 + xrow) * C_ + xg * 16;

    float4 xr0, xr1, xr2, xr3;

    #define STAGE_W(buf, kc) do {                                                  \
        _Pragma("unroll")                                                          \
        for (int kk = 0; kk < 2; kk++)                                             \
            _Pragma("unroll")                                                      \
            for (int i = 0; i < 2; i++)                                            \
                gld16(&Ws[buf][kk][wave * 32 + i * 16][0],                         \
                      wsrc + (size_t)i * 16 * C_ + (kc) + kk * 32);                \
    } while (0)
    #define LOAD_X(kc) do {                                                        \
        const float* xp = xsrc + (kc);                                             \
        xr0 = *(const float4*)xp;       xr1 = *(const float4*)(xp + 4);            \
        xr2 = *(const float4*)(xp + 8); xr3 = *(const float4*)(xp + 12);           \
    } while (0)
    #define WRITE_X(buf) do {                                                      \
        uint4 u0 = { pk2bf(xr0.x, xr0.y), pk2bf(xr0.z, xr0.w),                     \
                     pk2bf(xr1.x, xr1.y), pk2bf(xr1.z, xr1.w) };                   \
        uint4 u1 = { pk2bf(xr2.x, xr2.y), pk2bf(xr2.z, xr2.w),                     \
                     pk2bf(xr3.x, xr3.y), pk2bf(xr3.z, xr3.w) };                   \
        *(uint4*)&Xs[buf][xkk][xrow][xoff]     = u0;                               \
        *(uint4*)&Xs[buf][xkk][xrow][xoff + 8] = u1;                               \
    } while (0)

    STAGE_W(0, 0);
    LOAD_X(0);
    WRITE_X(0);

    for (int it = 0; it < 16; it++) {
        __syncthreads();                    // buf[it&1] ready (barrier drains vmcnt+LDS)
        const int buf = it & 1;
        if (it < 15) {
            STAGE_W(buf ^ 1, (it + 1) * 64);   // async, lands by next barrier
            LOAD_X((it + 1) * 64);             // in flight across compute
        }
        #pragma unroll
        for (int kk = 0; kk < 2; kk++) {
            bf16x8 af[4], bfr[2];
            #pragma unroll
            for (int mf = 0; mf < 4; mf++) af[mf]  = *(bf16x8*)&Xs[buf][kk][mf * 16 + l16][quad * 8];
            #pragma unroll
            for (int nf = 0; nf < 2; nf++) bfr[nf] = *(bf16x8*)&Ws[buf][kk][wave * 32 + nf * 16 + l16][quad * 8];
            #pragma unroll
            for (int nf = 0; nf < 2; nf++)
                #pragma unroll
                for (int mf = 0; mf < 4; mf++)
                    acc[mf][nf] = MFMA16(af[mf], bfr[nf], acc[mf][nf]);
        }
        if (it < 15) WRITE_X(buf ^ 1);      // x regs landed during compute
    }
    #undef STAGE_W
    #undef LOAD_X
    #undef WRITE_X

    unsigned short* dst = (nsel == 0) ? Q : (nsel == 1 ? K : V);
    #pragma unroll
    for (int mf = 0; mf < 4; mf++)
        #pragma unroll
        for (int nf = 0; nf < 2; nf++) {
            int c = wave * 32 + nf * 16 + l16;
            #pragma unroll
            for (int r = 0; r < 4; r++)
                dst[(size_t)(m0 + mf * 16 + quad * 4 + r) * H_ + c] = f2bf(acc[mf][nf][r]);
        }
}

// ---------- kernel 3: split-K flash causal attention (S^T layout) ----------
// grid (256, 8): bx -> {s = bx&7, qt = 31-(bx>>3)}, y = batch. K-tile 64, split 256.
__global__ __launch_bounds__(256, 4) void attn(const unsigned short* __restrict__ Qg,
                                               const unsigned short* __restrict__ Kg,
                                               const unsigned short* __restrict__ Vg,
                                               unsigned short* __restrict__ Ob,
                                               float* __restrict__ Ml) {
    const int bx = blockIdx.x;
    const int s  = bx & 7, qt = 31 - (bx >> 3);
    const int b  = blockIdx.y;
    const int qbase = qt * 64, kstart = s * 256;
    if (kstart > qbase) return;                               // inactive split
    const int kend  = (kstart + 256 < qbase + 64) ? kstart + 256 : qbase + 64;
    const int niter = (kend - kstart) >> 6;

    __shared__ unsigned short Ks[4][64][32];   // 16 KB (chunked by H/32)
    __shared__ unsigned short Vt[128 * 64];    // 16 KB (packed-pair XOR-swizzled transpose)
    __shared__ unsigned short Ps[4][16][64];   //  8 KB (per-wave P^T->A, XOR-swizzled)

    const int tid = threadIdx.x, wave = tid >> 6, lane = tid & 63;
    const int quad = lane >> 4, l16 = lane & 15;
    const size_t base = (size_t)b * T_ * H_;

    // K staging (async) + V regs
    const unsigned short* ksrc = Kg + base + (size_t)(kstart + (lane >> 2)) * H_ + wave * 32 + (lane & 3) * 8;
    #pragma unroll
    for (int p = 0; p < 4; p++) gld16(&Ks[wave][p * 16][0], ksrc + (size_t)p * 16 * H_);
    const unsigned short* vsrc = Vg + base + (size_t)(kstart + wave * 8 + quad * 2) * H_ + l16 * 8;
    u16x8 vr[2][2];
    vr[0][0] = *(const u16x8*)vsrc;             vr[0][1] = *(const u16x8*)(vsrc + H_);
    vr[1][0] = *(const u16x8*)(vsrc + 32 * H_); vr[1][1] = *(const u16x8*)(vsrc + 33 * H_);

    // Q fragments straight from global (loop-invariant)
    bf16x8 qf[4];
    const unsigned short* qp = Qg + base + (size_t)(qbase + wave * 16 + l16) * H_ + quad * 8;
    #pragma unroll
    for (int kk = 0; kk < 4; kk++) qf[kk] = *(const bf16x8*)(qp + kk * 32);

    f32x4 o[8];
    #pragma unroll
    for (int i = 0; i < 8; i++) o[i] = {0.f, 0.f, 0.f, 0.f};
    float m_i = -INFINITY, l_i = 0.f;
    const int swz = (l16 & 7) << 3;
    const int qg = qbase + wave * 16 + l16;    // this lane's q-row

    __syncthreads();                           // Ks(0) landed (barrier drains vmcnt)

    // write Vt(0): packed pairs, XOR swizzle (2-way = free)
    #pragma unroll
    for (int g = 0; g < 2; g++) {
        int t0 = wave * 8 + g * 32 + quad * 2;
        int t8 = t0 >> 3;
        #pragma unroll
        for (int j = 0; j < 8; j++) {
            int h = l16 * 8 + j;
            unsigned pk = (unsigned)(unsigned short)vr[g][0][j] | ((unsigned)(unsigned short)vr[g][1][j] << 16);
            int blk = (t8 ^ (h & 7) ^ ((h >> 3) & 7)) & 7;
            *(unsigned*)&Vt[h * 64 + blk * 8 + (t0 & 7)] = pk;
        }
    }

    for (int kt = 0; ; kt++) {
        const int kbase = kstart + kt * 64;
        // ---- S^T = K Q^T : rows k (quad*4+r within nf*16), col q = l16
        f32x4 st[4];
        #pragma unroll
        for (int nf = 0; nf < 4; nf++) st[nf] = {0.f, 0.f, 0.f, 0.f};
        #pragma unroll
        for (int kk = 0; kk < 4; kk++)
            #pragma unroll
            for (int nf = 0; nf < 4; nf++) {
                bf16x8 kfr = *(bf16x8*)&Ks[kk][nf * 16 + l16][quad * 8];
                st[nf] = MFMA16(kfr, qf[kk], st[nf]);
            }
        // ---- causal mask (diagonal region only; block-uniform branch)
        if (kbase + 64 > qbase) {
            #pragma unroll
            for (int nf = 0; nf < 4; nf++) {
                int kg = kbase + nf * 16 + quad * 4;
                #pragma unroll
                for (int r = 0; r < 4; r++)
                    if (kg + r > qg) st[nf][r] = -INFINITY;
            }
        }
        // ---- online softmax: per-lane q, 15 reg-max + 2 shuffles
        float mx = st[0][0];
        #pragma unroll
        for (int nf = 0; nf < 4; nf++)
            #pragma unroll
            for (int r = 0; r < 4; r++) mx = fmaxf(mx, st[nf][r]);
        mx = fmaxf(mx, __shfl_xor(mx, 16, 64));
        mx = fmaxf(mx, __shfl_xor(mx, 32, 64));
        float mnew = fmaxf(m_i, mx);
        float al = __expf(m_i - mnew);
        m_i = mnew;
        float rs = 0.f;
        #pragma unroll
        for (int nf = 0; nf < 4; nf++)
            #pragma unroll
            for (int r = 0; r < 4; r++) {
                float e = __expf(st[nf][r] - mnew);
                st[nf][r] = e; rs += e;
            }
        rs += __shfl_xor(rs, 16, 64);
        rs += __shfl_xor(rs, 32, 64);
        l_i = al * l_i + rs;
        // ---- P^T -> Ps (A-layout source), packed b64 writes, swizzled
        #pragma unroll
        for (int nf = 0; nf < 4; nf++) {
            uint2 pk = { pk2bf(st[nf][0], st[nf][1]), pk2bf(st[nf][2], st[nf][3]) };
            *(uint2*)&Ps[wave][l16][(nf * 16 + quad * 4) ^ swz] = pk;
        }
        // ---- rescale O (alpha lives at lane l16=q; O rows are quad*4+r)
        float a0 = __shfl(al, quad * 4 + 0, 64), a1 = __shfl(al, quad * 4 + 1, 64);
        float a2 = __shfl(al, quad * 4 + 2, 64), a3 = __shfl(al, quad * 4 + 3, 64);
        #pragma unroll
        for (int i = 0; i < 8; i++) {
            o[i][0] *= a0; o[i][1] *= a1; o[i][2] *= a2; o[i][3] *= a3;
        }
        __syncthreads();   // B: Vt complete, all Ks reads done

        const bool more = (kt + 1 < niter);
        if (more) {        // async prefetch next K; V tile -> regs
            ksrc += 64 * H_;
            #pragma unroll
            for (int p = 0; p < 4; p++) gld16(&Ks[wave][p * 16][0], ksrc + (size_t)p * 16 * H_);
            vsrc += 64 * H_;
            vr[0][0] = *(const u16x8*)vsrc;             vr[0][1] = *(const u16x8*)(vsrc + H_);
            vr[1][0] = *(const u16x8*)(vsrc + 32 * H_); vr[1][1] = *(const u16x8*)(vsrc + 33 * H_);
        }
        // ---- O += P V (overlaps in-flight prefetch)
        bf16x8 pa0 = *(bf16x8*)&Ps[wave][l16][(quad * 8) ^ swz];
        bf16x8 pa1 = *(bf16x8*)&Ps[wave][l16][(32 + quad * 8) ^ swz];
        #pragma unroll
        for (int nf = 0; nf < 8; nf++) {
            int h = nf * 16 + l16;
            int ex = (h & 7) ^ ((h >> 3) & 7);
            bf16x8 v0 = *(bf16x8*)&Vt[h * 64 + ((quad ^ ex) & 7) * 8];
            bf16x8 v1 = *(bf16x8*)&Vt[h * 64 + (((quad + 4) ^ ex) & 7) * 8];
            o[nf] = MFMA16(pa0, v0, o[nf]);
            o[nf] = MFMA16(pa1, v1, o[nf]);
        }
        if (!more) break;
        __syncthreads();   // A: next Ks landed; Vt free to overwrite
        #pragma unroll
        for (int g = 0; g < 2; g++) {
            int t0 = wave * 8 + g * 32 + quad * 2;
            int t8 = t0 >> 3;
            #pragma unroll
            for (int j = 0; j < 8; j++) {
                int h = l16 * 8 + j;
                unsigned pk = (unsigned)(unsigned short)vr[g][0][j] | ((unsigned)(unsigned short)vr[g][1][j] << 16);
                int blk = (t8 ^ (h & 7) ^ ((h >> 3) & 7)) & 7;
                *(unsigned*)&Vt[h * 64 + blk * 8 + (t0 & 7)] = pk;
            }
        }
    }

    // ---- partial epilogue: normalized O (bf16) + (m,l) per row
    const int g2 = qt >> 2;
    const int Pq = 2 * g2 * (g2 + 1) + (qt & 3) * (g2 + 1);   // prefix of split counts
    const int slot = (Pq + s) * NB + b;
    float lq[4];
    #pragma unroll
    for (int r = 0; r < 4; r++) lq[r] = __shfl(l_i, quad * 4 + r, 64);
    const size_t obase = (size_t)slot * 64 * 128;
    #pragma unroll
    for (int r = 0; r < 4; r++) {
        float invl = 1.0f / lq[r];
        #pragma unroll
        for (int nf = 0; nf < 8; nf++)
            Ob[obase + (size_t)(wave * 16 + quad * 4 + r) * 128 + nf * 16 + l16] = f2bf(o[nf][r] * invl);
    }
    if (lane < 16) {
        int ridx = slot * 64 + wave * 16 + l16;
        Ml[ridx * 2]     = m_i;
        Ml[ridx * 2 + 1] = l_i;
    }
}

// ---------- kernel 4: merge splits (log-sum-exp recombination) ----------
__global__ __launch_bounds__(256) void merge(const unsigned short* __restrict__ Ob,
                                             const float* __restrict__ Ml,
                                             float* __restrict__ out) {
    const int qt = blockIdx.x, b = blockIdx.y;
    const int g = qt >> 2;
    const int Pq = 2 * g * (g + 1) + (qt & 3) * (g + 1);
    const int ns = g + 1;
    const int tid = threadIdx.x;
    const int row = tid >> 2, c0 = (tid & 3) * 32;

    float mv[8], lv[8], mg = -INFINITY;
    for (int s2 = 0; s2 < ns; s2++) {
        int slot = (Pq + s2) * NB + b;
        mv[s2] = Ml[(slot * 64 + row) * 2];
        lv[s2] = Ml[(slot * 64 + row) * 2 + 1];
        mg = fmaxf(mg, mv[s2]);
    }
    float L = 0.f, w[8];
    for (int s2 = 0; s2 < ns; s2++) { w[s2] = lv[s2] * __expf(mv[s2] - mg); L += w[s2]; }
    float inv = 1.0f / L;

    float accv[32];
    #pragma unroll
    for (int i = 0; i < 32; i++) accv[i] = 0.f;
    for (int s2 = 0; s2 < ns; s2++) {
        int slot = (Pq + s2) * NB + b;
        const unsigned short* op = Ob + ((size_t)(slot * 64 + row)) * 128 + c0;
        #pragma unroll
        for (int cc = 0; cc < 4; cc++) {
            u16x8 v = *(const u16x8*)(op + cc * 8);
            #pragma unroll
            for (int j = 0; j < 8; j++) accv[cc * 8 + j] += w[s2] * bf2f(v[j]);
        }
    }
    float* od = out + ((size_t)(b * T_ + qt * 64 + row)) * 128 + c0;
    #pragma unroll
    for (int cc = 0; cc < 8; cc++) {
        float4 w4 = { accv[cc*4] * inv, accv[cc*4+1] * inv, accv[cc*4+2] * inv, accv[cc*4+3] * inv };
        *(float4*)(od + cc * 4) = w4;
    }
}

extern "C" void kernel_launch(void* const* d_in, const int* in_sizes, int n_in,
                              void* d_out, int out_size, void* d_ws, size_t ws_size,
                              hipStream_t stream) {
    const float* x  = (const float*)d_in[0];
    const float* Wq = (const float*)d_in[1];
    const float* Wk = (const float*)d_in[2];
    const float* Wv = (const float*)d_in[3];

    char* ws = (char*)d_ws;
    unsigned short* Wb = (unsigned short*)ws;                          // 0.75 MB @ 0
    unsigned short* Q  = (unsigned short*)(ws + (size_t) 1 * (1u << 20)); // 4 MB
    unsigned short* K  = (unsigned short*)(ws + (size_t) 5 * (1u << 20));
    unsigned short* V  = (unsigned short*)(ws + (size_t) 9 * (1u << 20));
    unsigned short* Ob = (unsigned short*)(ws + (size_t)13 * (1u << 20)); // 18.9 MB (1152 slots)
    float*          Ml = (float*)(ws + (size_t)32 * (1u << 20));          // 0.6 MB
    float* out = (float*)d_out;

    hipLaunchKernelGGL(wconv, dim3(192), dim3(256), 0, stream, Wq, Wk, Wv, Wb);
    hipLaunchKernelGGL(proj,  dim3(3, 256), dim3(256), 0, stream, x, Wb, Q, K, V);
    hipLaunchKernelGGL(attn,  dim3(256, NB), dim3(256), 0, stream, Q, K, V, Ob, Ml);
    hipLaunchKernelGGL(merge, dim3(32, NB), dim3(256), 0, stream, Ob, Ml, out);
}